// Round 17
// baseline (373.200 us; speedup 1.0000x reference)
//
#include <hip/hip_runtime.h>
#include <cstdint>
#include <cstddef>

#define NF 128          // feature width (IN_F == HID_F == 128)
#define ELLW 16         // ELL slots per node (P(deg>16) ~ 1.6e-4 for Poisson-6)
#define OVF_CAP 65536   // overflow edges (deg>ELLW)

typedef __attribute__((ext_vector_type(4))) float f32x4;
typedef __attribute__((ext_vector_type(8))) short bf16x8;

#define GL2LDS16(g, l) __builtin_amdgcn_global_load_lds(                     \
    (const __attribute__((address_space(1))) unsigned*)(g),                  \
    (__attribute__((address_space(3))) unsigned*)(l), 16, 0, 0)

static __device__ inline float bf2f(short u) {
    union { unsigned u; float f; } v;
    v.u = ((unsigned)(unsigned short)u) << 16;
    return v.f;
}
static __device__ inline short f2bf(float f) {
    union { float f; unsigned u; } v; v.f = f;
    unsigned r = v.u + 0x7FFF + ((v.u >> 16) & 1);  // RNE
    return (short)(r >> 16);
}
static __device__ inline float u2f(unsigned u) {
    union { unsigned u; float f; } v; v.u = u; return v.f;
}
static __device__ inline unsigned f2u(float f) {
    union { float f; unsigned u; } v; v.f = f; return v.u;
}
static __device__ inline unsigned packbf(float lo, float hi) {
    unsigned ul = f2u(lo), uh = f2u(hi);
    ul = ul + 0x7FFF + ((ul >> 16) & 1);
    uh = uh + 0x7FFF + ((uh >> 16) & 1);
    return (ul >> 16) | (uh & 0xFFFF0000u);
}

// ---------------- fused prologue: ELL-16 build + feature cvt + weight FOLD/cvt ----------------
// Chebyshev weight folding:  Y = X0(W0-W1+W2)^T + Z1(W1-4W2)^T + Z2'(2W2)^T.

static __global__ __launch_bounds__(256) void k_pro(
    const int* __restrict__ esrc, const int* __restrict__ edst, int ne,
    int* __restrict__ cnt, int* __restrict__ ell,
    int* __restrict__ ovf_cnt, int2* __restrict__ ovf,
    const float* __restrict__ feat, short* __restrict__ fbf, int n8, int nbE, int nbF,
    const float* __restrict__ w1, const float* __restrict__ w3,
    const float* __restrict__ wm1, const float* __restrict__ wm2,
    short* __restrict__ o1, short* __restrict__ o3,
    short* __restrict__ om1, short* __restrict__ om2) {
    int b = blockIdx.x;
    if (b < nbE) {
        int e = b * 256 + threadIdx.x;
        if (e < ne) {
            int d = edst[e], s = esrc[e];
            int r = atomicAdd(&cnt[d], 1);
            if (r < ELLW) ell[(size_t)d * ELLW + r] = s;
            else {
                int o = atomicAdd(ovf_cnt, 1);
                if (o < OVF_CAP) ovf[o] = make_int2(d, s);
            }
        }
        return;
    }
    b -= nbE;
    if (b < nbF) {
        int i = b * 256 + threadIdx.x;
        if (i < n8) {
            f32x4 a = *(const f32x4*)&feat[(size_t)i * 8];
            f32x4 c = *(const f32x4*)&feat[(size_t)i * 8 + 4];
            bf16x8 r;
            r[0] = f2bf(a[0]); r[1] = f2bf(a[1]); r[2] = f2bf(a[2]); r[3] = f2bf(a[3]);
            r[4] = f2bf(c[0]); r[5] = f2bf(c[1]); r[6] = f2bf(c[2]); r[7] = f2bf(c[3]);
            *(bf16x8*)&fbf[(size_t)i * 8] = r;
        }
        return;
    }
    b -= nbF;
    int i = b * 256 + threadIdx.x;   // 0..15359
    if (i < 12288) {
        const float* x = (i < 6144) ? w1 : w3;
        short* y       = (i < 6144) ? o1 : o3;
        int ii = (i < 6144) ? i : i - 6144;
        int r = ii / 48, c = ii % 48;
        int kt = c * 8, seg = kt >> 7, o = kt & 127;
        const float* base = x + (size_t)r * 384;
        float c0, c1, c2;
        if (seg == 0)      { c0 = 1.f;  c1 = -1.f; c2 = 1.f;  }
        else if (seg == 1) { c0 = 0.f;  c1 = 1.f;  c2 = -4.f; }
        else               { c0 = 0.f;  c1 = 0.f;  c2 = 2.f;  }
        bf16x8 rr;
#pragma unroll
        for (int h = 0; h < 2; ++h) {
            f32x4 a0 = *(const f32x4*)&base[o + h * 4];
            f32x4 a1 = *(const f32x4*)&base[128 + o + h * 4];
            f32x4 a2 = *(const f32x4*)&base[256 + o + h * 4];
#pragma unroll
            for (int j = 0; j < 4; ++j)
                rr[h * 4 + j] = f2bf(c0 * a0[j] + c1 * a1[j] + c2 * a2[j]);
        }
        *(bf16x8*)&y[(size_t)r * 384 + kt] = rr;
        return;
    }
    const float* x; short* y; int off;
    if (i < 14336) { x = wm1; y = om1; off = i - 12288; }
    else           { x = wm2; y = om2; off = i - 14336; }
    f32x4 a = *(const f32x4*)&x[(size_t)off * 8];
    f32x4 c = *(const f32x4*)&x[(size_t)off * 8 + 4];
    bf16x8 r;
    r[0] = f2bf(a[0]); r[1] = f2bf(a[1]); r[2] = f2bf(a[2]); r[3] = f2bf(a[3]);
    r[4] = f2bf(c[0]); r[5] = f2bf(c[1]); r[6] = f2bf(c[2]); r[7] = f2bf(c[3]);
    *(bf16x8*)&y[(size_t)off * 8] = r;
}

// ---------------- pure aggregation: out = dinv_i * sum_src Xin[src]*dinv[src] ----------------
// ELL-16; FIRST lap gathers dinv=rsqrt(cnt[src]) and caches (src,dinv) pairs in ell2
// (coalesced 128B/node); later laps read pairs directly. Overflow list for deg>16.

template <bool FIRST>
static __global__ __launch_bounds__(256) void k_lap(
    const short* __restrict__ Xin,
    const int* __restrict__ cnt, const int* __restrict__ ell, int2* __restrict__ ell2,
    const int* __restrict__ ovf_cnt, const int2* __restrict__ ovf,
    short* __restrict__ out, int n) {
    int node = blockIdx.x * 4 + (threadIdx.x >> 6);
    if (node >= n) return;
    int l = threadIdx.x & 63;
    const unsigned* Xu = (const unsigned*)Xin;
    int deg = cnt[node];
    int dcap = deg < ELLW ? deg : ELLW;

    int myi = 0; float mydv = 0.f;
    if (l < ELLW) {
        if (FIRST) {
            if (l < dcap) {
                myi = ell[(size_t)node * ELLW + l];
                mydv = rsqrtf(fmaxf((float)cnt[myi], 1.f));
            }
            ell2[(size_t)node * ELLW + l] = make_int2(myi, (int)f2u(mydv));
        } else {
            int2 q = ell2[(size_t)node * ELLW + l];
            myi = q.x; mydv = u2f((unsigned)q.y);
        }
    }

    float s0 = 0.f, s1 = 0.f;
    for (int base = 0; base < dcap; base += 8) {
        unsigned v[8]; float dv[8];
#pragma unroll
        for (int j = 0; j < 8; ++j) {
            int jj = base + j;
            bool act = (jj < dcap);                       // wave-uniform
            int lane = act ? jj : base;
            int src = __builtin_amdgcn_readlane(myi, lane);
            unsigned dvb = __builtin_amdgcn_readlane((int)f2u(mydv), lane);
            dv[j] = act ? u2f(dvb) : 0.f;
            v[j] = Xu[(size_t)src * 64 + l];
        }
#pragma unroll
        for (int j = 0; j < 8; ++j) {
            s0 += u2f(v[j] << 16) * dv[j];
            s1 += u2f(v[j] & 0xFFFF0000u) * dv[j];
        }
    }
    // overflow edges (deg > ELLW): wave-uniform scan of the tiny global list
    int novf = *ovf_cnt;
    if (novf > 0) {
        if (novf > OVF_CAP) novf = OVF_CAP;
        for (int k = 0; k < novf; ++k) {
            int2 q2 = ovf[k];
            if (q2.x == node) {
                float dw = rsqrtf(fmaxf((float)cnt[q2.y], 1.f));
                unsigned v = Xu[(size_t)q2.y * 64 + l];
                s0 += u2f(v << 16) * dw;
                s1 += u2f(v & 0xFFFF0000u) * dw;
            }
        }
    }

    float di = rsqrtf(fmaxf((float)deg, 1.f));
    ((unsigned*)out)[(size_t)node * 64 + l] = packbf(s0 * di, s1 * di);
}

// ---------------- conv1 GEMM (R11 structure) ----------------

static __global__ __launch_bounds__(512) void k_gemm_conv(
    const short* __restrict__ X0, const short* __restrict__ X1, const short* __restrict__ X2,
    const short* __restrict__ Wbf, const float* __restrict__ bias,
    const float* __restrict__ bng, const float* __restrict__ bnb,
    const float* __restrict__ bnm, const float* __restrict__ bnv,
    int M, short* __restrict__ out) {
    __shared__ short As[2][128 * 32];
    __shared__ short Bs[2][128 * 32];

    const int nwg = gridDim.x;
    const int q = nwg >> 3, r = nwg & 7;
    const int xcd = blockIdx.x & 7, slot = blockIdx.x >> 3;
    const int flat = (xcd < r ? xcd * (q + 1) : r * (q + 1) + (xcd - r) * q) + slot;
    const int m0 = flat * 128;

    const int t = threadIdx.x;
    const int wv = t >> 6;
    const int ln = t & 63;
    const int wr = wv >> 2;
    const int wc = wv & 3;
    const int lr = ln & 15;
    const int lk = ln >> 4;

    const short* segs[3] = {X0, X1, X2};

    f32x4 acc[4][2];
#pragma unroll
    for (int i = 0; i < 4; ++i)
#pragma unroll
        for (int j = 0; j < 2; ++j) acc[i][j] = (f32x4){0.f, 0.f, 0.f, 0.f};

    auto issue = [&](int buf, int kt) {
        const short* Xp = segs[kt >> 7];
        const int klocal = kt & 127;
#pragma unroll
        for (int j = 0; j < 2; ++j) {
            int g = wv * 2 + j;
            int c = g * 64 + ln;
            if (g < 8) {
                int row = c >> 2, sl = c & 3;
                int gm = m0 + row;
                if (gm > M - 1) gm = M - 1;
                const short* src = &Xp[(size_t)gm * 128 + klocal + ((sl ^ ((row >> 1) & 3)) * 8)];
                GL2LDS16(src, &As[buf][g * 512]);
            } else {
                int cb = c - 512;
                int row = cb >> 2, sl = cb & 3;
                const short* src = &Wbf[(size_t)row * 384 + kt + ((sl ^ ((row >> 1) & 3)) * 8)];
                GL2LDS16(src, &Bs[buf][(g - 8) * 512]);
            }
        }
    };
    auto compute = [&](int buf) {
        bf16x8 af[4], bfr[2];
#pragma unroll
        for (int fi = 0; fi < 4; ++fi) {
            int row = wr * 64 + fi * 16 + lr;
            af[fi] = *(const bf16x8*)&As[buf][row * 32 + ((lk ^ ((row >> 1) & 3)) * 8)];
        }
#pragma unroll
        for (int fj = 0; fj < 2; ++fj) {
            int row = wc * 32 + fj * 16 + lr;
            bfr[fj] = *(const bf16x8*)&Bs[buf][row * 32 + ((lk ^ ((row >> 1) & 3)) * 8)];
        }
#pragma unroll
        for (int fi = 0; fi < 4; ++fi)
#pragma unroll
            for (int fj = 0; fj < 2; ++fj)
                acc[fi][fj] = __builtin_amdgcn_mfma_f32_16x16x32_bf16(af[fi], bfr[fj], acc[fi][fj], 0, 0, 0);
    };

    issue(0, 0);
    __syncthreads();
#pragma unroll
    for (int tgt = 0; tgt < 12; ++tgt) {
        if (tgt < 11) issue((tgt + 1) & 1, (tgt + 1) * 32);
        compute(tgt & 1);
        __syncthreads();
    }

#pragma unroll
    for (int fi = 0; fi < 4; ++fi) {
#pragma unroll
        for (int reg = 0; reg < 4; ++reg) {
            int gm = m0 + wr * 64 + fi * 16 + lk * 4 + reg;
            if (gm >= M) continue;
#pragma unroll
            for (int fj = 0; fj < 2; ++fj) {
                int gn = wc * 32 + fj * 16 + lr;
                float y = fmaxf(acc[fi][fj][reg] + bias[gn], 0.f);
                float sc = rsqrtf(bnv[gn] + 1e-5f) * bng[gn];
                y = (y - bnm[gn]) * sc + bnb[gn];
                out[(size_t)gm * 128 + gn] = f2bf(y);
            }
        }
    }
}

// ---------------- conv2 GEMM + fused MLP ----------------

static __global__ __launch_bounds__(512) void k_gemm_mlp(
    const short* __restrict__ X0, const short* __restrict__ X1, const short* __restrict__ X2,
    const short* __restrict__ Wbf, const float* __restrict__ bias,
    const short* __restrict__ res,
    const short* __restrict__ Wm1bf, const float* __restrict__ bm1,
    const short* __restrict__ Wm2bf, const float* __restrict__ bm2,
    int M, float* __restrict__ out) {
    __shared__ __align__(16) short smem[25600];
    short* As0 = smem;
    short* As1 = smem + 4096;
    short* Bs0 = smem + 8192;
    short* Bs1 = smem + 12288;
    short* hs  = smem;            // [128][136] after GEMM phase
    short* Wst = smem + 17408;    // 2 x 4096 (MLP1) / 8192 whole-Wm2 (MLP2)

    const int nwg = gridDim.x;
    const int q = nwg >> 3, r = nwg & 7;
    const int xcd = blockIdx.x & 7, slot = blockIdx.x >> 3;
    const int flat = (xcd < r ? xcd * (q + 1) : r * (q + 1) + (xcd - r) * q) + slot;
    const int m0 = flat * 128;

    const int t = threadIdx.x;
    const int wv = t >> 6;
    const int ln = t & 63;
    const int wr = wv >> 2;
    const int wc = wv & 3;
    const int lr = ln & 15;
    const int lk = ln >> 4;

    const short* segs[3] = {X0, X1, X2};

    f32x4 acc[4][2];
#pragma unroll
    for (int i = 0; i < 4; ++i)
#pragma unroll
        for (int j = 0; j < 2; ++j) acc[i][j] = (f32x4){0.f, 0.f, 0.f, 0.f};

    auto issue = [&](int buf, int kt) {
        const short* Xp = segs[kt >> 7];
        const int klocal = kt & 127;
        short* Ab = buf ? As1 : As0;
        short* Bb = buf ? Bs1 : Bs0;
#pragma unroll
        for (int j = 0; j < 2; ++j) {
            int g = wv * 2 + j;
            int c = g * 64 + ln;
            if (g < 8) {
                int row = c >> 2, sl = c & 3;
                int gm = m0 + row;
                if (gm > M - 1) gm = M - 1;
                const short* src = &Xp[(size_t)gm * 128 + klocal + ((sl ^ ((row >> 1) & 3)) * 8)];
                GL2LDS16(src, &Ab[g * 512]);
            } else {
                int cb = c - 512;
                int row = cb >> 2, sl = cb & 3;
                const short* src = &Wbf[(size_t)row * 384 + kt + ((sl ^ ((row >> 1) & 3)) * 8)];
                GL2LDS16(src, &Bb[(g - 8) * 512]);
            }
        }
    };
    auto compute = [&](int buf) {
        short* Ab = buf ? As1 : As0;
        short* Bb = buf ? Bs1 : Bs0;
        bf16x8 af[4], bfr[2];
#pragma unroll
        for (int fi = 0; fi < 4; ++fi) {
            int row = wr * 64 + fi * 16 + lr;
            af[fi] = *(const bf16x8*)&Ab[row * 32 + ((lk ^ ((row >> 1) & 3)) * 8)];
        }
#pragma unroll
        for (int fj = 0; fj < 2; ++fj) {
            int row = wc * 32 + fj * 16 + lr;
            bfr[fj] = *(const bf16x8*)&Bb[row * 32 + ((lk ^ ((row >> 1) & 3)) * 8)];
        }
#pragma unroll
        for (int fi = 0; fi < 4; ++fi)
#pragma unroll
            for (int fj = 0; fj < 2; ++fj)
                acc[fi][fj] = __builtin_amdgcn_mfma_f32_16x16x32_bf16(af[fi], bfr[fj], acc[fi][fj], 0, 0, 0);
    };

    issue(0, 0);
    __syncthreads();
#pragma unroll
    for (int tgt = 0; tgt < 12; ++tgt) {
        if (tgt < 11) issue((tgt + 1) & 1, (tgt + 1) * 32);
        compute(tgt & 1);
        __syncthreads();
    }

    auto issueW1 = [&](int buf, int kt) {
        int c = t;
        int row = c >> 2, sl = c & 3;
        const short* src = &Wm1bf[(size_t)row * 128 + kt + ((sl ^ ((row >> 1) & 3)) * 8)];
        GL2LDS16(src, &Wst[buf * 4096 + c * 8]);
    };
    issueW1(0, 0);

#pragma unroll
    for (int fi = 0; fi < 4; ++fi) {
#pragma unroll
        for (int reg = 0; reg < 4; ++reg) {
            int row = wr * 64 + fi * 16 + lk * 4 + reg;
            int gm = m0 + row;
            int gr = gm < M ? gm : M - 1;
#pragma unroll
            for (int fj = 0; fj < 2; ++fj) {
                int gn = wc * 32 + fj * 16 + lr;
                float y = fmaxf(acc[fi][fj][reg] + bias[gn], 0.f) + bf2f(res[(size_t)gr * 128 + gn]);
                hs[row * 136 + gn] = f2bf(y);
            }
        }
    }
    __syncthreads();

    f32x4 acc2[4][2];
#pragma unroll
    for (int i = 0; i < 4; ++i)
#pragma unroll
        for (int j = 0; j < 2; ++j) acc2[i][j] = (f32x4){0.f, 0.f, 0.f, 0.f};

#pragma unroll
    for (int s = 0; s < 4; ++s) {
        if (s < 3) issueW1((s + 1) & 1, (s + 1) * 32);
        int kt = s * 32;
        short* Wb = &Wst[(s & 1) * 4096];
        bf16x8 af[4], bw[2];
#pragma unroll
        for (int fi = 0; fi < 4; ++fi) {
            int row = wr * 64 + fi * 16 + lr;
            af[fi] = *(const bf16x8*)&hs[row * 136 + kt + lk * 8];
        }
#pragma unroll
        for (int fj = 0; fj < 2; ++fj) {
            int row = wc * 32 + fj * 16 + lr;
            bw[fj] = *(const bf16x8*)&Wb[row * 32 + ((lk ^ ((row >> 1) & 3)) * 8)];
        }
#pragma unroll
        for (int fi = 0; fi < 4; ++fi)
#pragma unroll
            for (int fj = 0; fj < 2; ++fj)
                acc2[fi][fj] = __builtin_amdgcn_mfma_f32_16x16x32_bf16(af[fi], bw[fj], acc2[fi][fj], 0, 0, 0);
        __syncthreads();
    }

#pragma unroll
    for (int j = 0; j < 2; ++j) {
        int c = j * 512 + t;
        int row = c >> 4, s = c & 15;
        const short* src = &Wm2bf[(size_t)row * 128 + ((s ^ (row & 7)) * 8)];
        GL2LDS16(src, &Wst[c * 8]);
    }
#pragma unroll
    for (int fi = 0; fi < 4; ++fi) {
#pragma unroll
        for (int reg = 0; reg < 4; ++reg) {
            int row = wr * 64 + fi * 16 + lk * 4 + reg;
#pragma unroll
            for (int fj = 0; fj < 2; ++fj) {
                int col = wc * 32 + fj * 16 + lr;
                hs[row * 136 + col] = f2bf(fmaxf(acc2[fi][fj][reg] + bm1[col], 0.f));
            }
        }
    }
    __syncthreads();

    f32x4 acc3[4];
#pragma unroll
    for (int i = 0; i < 4; ++i) acc3[i] = (f32x4){0.f, 0.f, 0.f, 0.f};
#pragma unroll
    for (int s = 0; s < 4; ++s) {
        int kt = s * 32;
        bf16x8 af, bw;
        int brow = wc * 16 + lr;
        int sidx = s * 4 + lk;
        bw = *(const bf16x8*)&Wst[brow * 128 + ((sidx ^ (brow & 7)) * 8)];
#pragma unroll
        for (int fi = 0; fi < 4; ++fi) {
            int row = wr * 64 + fi * 16 + lr;
            af = *(const bf16x8*)&hs[row * 136 + kt + lk * 8];
            acc3[fi] = __builtin_amdgcn_mfma_f32_16x16x32_bf16(af, bw, acc3[fi], 0, 0, 0);
        }
    }

#pragma unroll
    for (int fi = 0; fi < 4; ++fi) {
#pragma unroll
        for (int reg = 0; reg < 4; ++reg) {
            int gm = m0 + wr * 64 + fi * 16 + lk * 4 + reg;
            if (gm >= M) continue;
            int col = wc * 16 + lr;
            out[(size_t)gm * 64 + col] = acc3[fi][reg] + bm2[col];
        }
    }
}

// ---------------- launch ----------------

extern "C" void kernel_launch(void* const* d_in, const int* in_sizes, int n_in,
                              void* d_out, int out_size, void* d_ws, size_t ws_size,
                              hipStream_t stream) {
    const float* features = (const float*)d_in[0];
    const int*   esrc     = (const int*)d_in[1];
    const int*   edst     = (const int*)d_in[2];
    const float* W1   = (const float*)d_in[3];
    const float* b1   = (const float*)d_in[4];
    const float* bng  = (const float*)d_in[5];
    const float* bnb  = (const float*)d_in[6];
    const float* bnm  = (const float*)d_in[7];
    const float* bnv  = (const float*)d_in[8];
    const float* W3   = (const float*)d_in[9];
    const float* b3   = (const float*)d_in[10];
    const float* Wm1  = (const float*)d_in[11];
    const float* bm1  = (const float*)d_in[12];
    const float* Wm2  = (const float*)d_in[13];
    const float* bm2  = (const float*)d_in[14];
    float* out = (float*)d_out;

    const int n  = in_sizes[0] / NF;     // 100000
    const int ne = in_sizes[1];          // 600000

    uint8_t* w = (uint8_t*)d_ws;
    size_t off = 0;
    auto alloc = [&](size_t bytes) -> void* {
        void* p = w + off;
        off = (off + bytes + 255) & ~(size_t)255;
        return p;
    };
    int* cnt      = (int*)alloc(((size_t)n + 1) * 4);   // [n] counts + [n] = ovf_cnt
    int* ell      = (int*)alloc((size_t)n * ELLW * 4);
    int2* ell2    = (int2*)alloc((size_t)n * ELLW * 8);
    int2* ovf     = (int2*)alloc((size_t)OVF_CAP * 8);
    short* fbf    = (short*)alloc((size_t)n * NF * 2);
    short* bufB   = (short*)alloc((size_t)n * NF * 2);   // Z1
    short* bufC   = (short*)alloc((size_t)n * NF * 2);   // Z2'
    short* bufD   = (short*)alloc((size_t)n * NF * 2);   // h1 (conv1 out, residual)
    short* W1bf   = (short*)alloc((size_t)128 * 384 * 2);  // folded
    short* W3bf   = (short*)alloc((size_t)128 * 384 * 2);  // folded
    short* Wm1bf  = (short*)alloc((size_t)128 * 128 * 2);
    short* Wm2bf  = (short*)alloc((size_t)64 * 128 * 2);
    (void)ws_size;
    int* ovf_cnt = cnt + n;

    const int TB = 256;
    const int nbE = (ne + TB - 1) / TB;
    const int n8  = n * NF / 8;
    const int nbF = (n8 + TB - 1) / TB;

    hipMemsetAsync(cnt, 0, ((size_t)n + 1) * 4, stream);
    k_pro<<<nbE + nbF + 60, TB, 0, stream>>>(esrc, edst, ne, cnt, ell, ovf_cnt, ovf,
                                             features, fbf, n8, nbE, nbF,
                                             W1, W3, Wm1, Wm2, W1bf, W3bf, Wm1bf, Wm2bf);

    const int gm128 = (n + 127) / 128;
    const int nbL   = (n + 3) / 4;   // lap: 4 nodes per 256-thread block

    // ---- conv1:  Z1 = P X0 (build pairs);  Z2' = P Z1;  h1 = bn(relu(GEMM)) ----
    k_lap<true><<<nbL, 256, 0, stream>>>(fbf, cnt, ell, ell2, ovf_cnt, ovf, bufB, n);
    k_lap<false><<<nbL, 256, 0, stream>>>(bufB, cnt, ell, ell2, ovf_cnt, ovf, bufC, n);
    k_gemm_conv<<<gm128, 512, 0, stream>>>(fbf, bufB, bufC, W1bf, b1,
                                           bng, bnb, bnm, bnv, n, bufD);

    // ---- conv2 + fused MLP ----
    k_lap<false><<<nbL, 256, 0, stream>>>(bufD, cnt, ell, ell2, ovf_cnt, ovf, bufB, n);
    k_lap<false><<<nbL, 256, 0, stream>>>(bufB, cnt, ell, ell2, ovf_cnt, ovf, bufC, n);
    k_gemm_mlp<<<gm128, 512, 0, stream>>>(bufD, bufB, bufC, W3bf, b3, bufD,
                                          Wm1bf, bm1, Wm2bf, bm2, n, out);
}

// Round 18
// 258.969 us; speedup vs baseline: 1.4411x; 1.4411x over previous
//
#include <hip/hip_runtime.h>
#include <cstdint>
#include <cstddef>

#define NF 128          // feature width (IN_F == HID_F == 128)
#define ELLW 16         // ELL slots per node (P(deg>16) ~ 1.5e-4 for Poisson-6)
#define OVF_CAP 65536   // overflow edges (deg>ELLW)

typedef __attribute__((ext_vector_type(4))) float f32x4;
typedef __attribute__((ext_vector_type(8))) short bf16x8;

#define GL2LDS16(g, l) __builtin_amdgcn_global_load_lds(                     \
    (const __attribute__((address_space(1))) unsigned*)(g),                  \
    (__attribute__((address_space(3))) unsigned*)(l), 16, 0, 0)

static __device__ inline float bf2f(short u) {
    union { unsigned u; float f; } v;
    v.u = ((unsigned)(unsigned short)u) << 16;
    return v.f;
}
static __device__ inline short f2bf(float f) {
    union { float f; unsigned u; } v; v.f = f;
    unsigned r = v.u + 0x7FFF + ((v.u >> 16) & 1);  // RNE
    return (short)(r >> 16);
}
static __device__ inline float u2f(unsigned u) {
    union { unsigned u; float f; } v; v.u = u; return v.f;
}
static __device__ inline unsigned f2u(float f) {
    union { float f; unsigned u; } v; v.f = f; return v.u;
}
static __device__ inline unsigned packbf(float lo, float hi) {
    unsigned ul = f2u(lo), uh = f2u(hi);
    ul = ul + 0x7FFF + ((ul >> 16) & 1);
    uh = uh + 0x7FFF + ((uh >> 16) & 1);
    return (ul >> 16) | (uh & 0xFFFF0000u);
}

// ---------------- fused prologue: ELL-16 build + feature cvt + weight FOLD/cvt ----------------
// Chebyshev weight folding:  Y = X0(W0-W1+W2)^T + Z1(W1-4W2)^T + Z2'(2W2)^T.

static __global__ __launch_bounds__(256) void k_pro(
    const int* __restrict__ esrc, const int* __restrict__ edst, int ne,
    int* __restrict__ cnt, int* __restrict__ ell,
    int* __restrict__ ovf_cnt, int2* __restrict__ ovf,
    const float* __restrict__ feat, short* __restrict__ fbf, int n8, int nbE, int nbF,
    const float* __restrict__ w1, const float* __restrict__ w3,
    const float* __restrict__ wm1, const float* __restrict__ wm2,
    short* __restrict__ o1, short* __restrict__ o3,
    short* __restrict__ om1, short* __restrict__ om2) {
    int b = blockIdx.x;
    if (b < nbE) {
        int e = b * 256 + threadIdx.x;
        if (e < ne) {
            int d = edst[e], s = esrc[e];
            int r = atomicAdd(&cnt[d], 1);
            if (r < ELLW) ell[(size_t)d * ELLW + r] = s;
            else {
                int o = atomicAdd(ovf_cnt, 1);
                if (o < OVF_CAP) ovf[o] = make_int2(d, s);
            }
        }
        return;
    }
    b -= nbE;
    if (b < nbF) {
        int i = b * 256 + threadIdx.x;
        if (i < n8) {
            f32x4 a = *(const f32x4*)&feat[(size_t)i * 8];
            f32x4 c = *(const f32x4*)&feat[(size_t)i * 8 + 4];
            bf16x8 r;
            r[0] = f2bf(a[0]); r[1] = f2bf(a[1]); r[2] = f2bf(a[2]); r[3] = f2bf(a[3]);
            r[4] = f2bf(c[0]); r[5] = f2bf(c[1]); r[6] = f2bf(c[2]); r[7] = f2bf(c[3]);
            *(bf16x8*)&fbf[(size_t)i * 8] = r;
        }
        return;
    }
    b -= nbF;
    int i = b * 256 + threadIdx.x;   // 0..15359
    if (i < 12288) {
        const float* x = (i < 6144) ? w1 : w3;
        short* y       = (i < 6144) ? o1 : o3;
        int ii = (i < 6144) ? i : i - 6144;
        int r = ii / 48, c = ii % 48;
        int kt = c * 8, seg = kt >> 7, o = kt & 127;
        const float* base = x + (size_t)r * 384;
        float c0, c1, c2;
        if (seg == 0)      { c0 = 1.f;  c1 = -1.f; c2 = 1.f;  }
        else if (seg == 1) { c0 = 0.f;  c1 = 1.f;  c2 = -4.f; }
        else               { c0 = 0.f;  c1 = 0.f;  c2 = 2.f;  }
        bf16x8 rr;
#pragma unroll
        for (int h = 0; h < 2; ++h) {
            f32x4 a0 = *(const f32x4*)&base[o + h * 4];
            f32x4 a1 = *(const f32x4*)&base[128 + o + h * 4];
            f32x4 a2 = *(const f32x4*)&base[256 + o + h * 4];
#pragma unroll
            for (int j = 0; j < 4; ++j)
                rr[h * 4 + j] = f2bf(c0 * a0[j] + c1 * a1[j] + c2 * a2[j]);
        }
        *(bf16x8*)&y[(size_t)r * 384 + kt] = rr;
        return;
    }
    const float* x; short* y; int off;
    if (i < 14336) { x = wm1; y = om1; off = i - 12288; }
    else           { x = wm2; y = om2; off = i - 14336; }
    f32x4 a = *(const f32x4*)&x[(size_t)off * 8];
    f32x4 c = *(const f32x4*)&x[(size_t)off * 8 + 4];
    bf16x8 r;
    r[0] = f2bf(a[0]); r[1] = f2bf(a[1]); r[2] = f2bf(a[2]); r[3] = f2bf(a[3]);
    r[4] = f2bf(c[0]); r[5] = f2bf(c[1]); r[6] = f2bf(c[2]); r[7] = f2bf(c[3]);
    *(bf16x8*)&y[(size_t)off * 8] = r;
}

// ---------------- pure aggregation: out = dinv_i * sum_src Xin[src]*dinv[src] ----------------
// ELL-16; FIRST lap gathers dinv=rsqrt(cnt[src]) and caches (src,dinv) pairs in ell2;
// later laps read pairs. Overflow scan GUARDED by deg>ELLW (only ~15/100k waves).

template <bool FIRST>
static __global__ __launch_bounds__(256) void k_lap(
    const short* __restrict__ Xin,
    const int* __restrict__ cnt, const int* __restrict__ ell, int2* __restrict__ ell2,
    const int* __restrict__ ovf_cnt, const int2* __restrict__ ovf,
    short* __restrict__ out, int n) {
    int node = blockIdx.x * 4 + (threadIdx.x >> 6);
    if (node >= n) return;
    int l = threadIdx.x & 63;
    const unsigned* Xu = (const unsigned*)Xin;
    int deg = cnt[node];
    int dcap = deg < ELLW ? deg : ELLW;

    int myi = 0; float mydv = 0.f;
    if (l < ELLW) {
        if (FIRST) {
            if (l < dcap) {
                myi = ell[(size_t)node * ELLW + l];
                mydv = rsqrtf(fmaxf((float)cnt[myi], 1.f));
            }
            ell2[(size_t)node * ELLW + l] = make_int2(myi, (int)f2u(mydv));
        } else {
            int2 q = ell2[(size_t)node * ELLW + l];
            myi = q.x; mydv = u2f((unsigned)q.y);
        }
    }

    float s0 = 0.f, s1 = 0.f;
    for (int base = 0; base < dcap; base += 8) {
        unsigned v[8]; float dv[8];
#pragma unroll
        for (int j = 0; j < 8; ++j) {
            int jj = base + j;
            bool act = (jj < dcap);                       // wave-uniform
            int lane = act ? jj : base;
            int src = __builtin_amdgcn_readlane(myi, lane);
            unsigned dvb = __builtin_amdgcn_readlane((int)f2u(mydv), lane);
            dv[j] = act ? u2f(dvb) : 0.f;
            v[j] = Xu[(size_t)src * 64 + l];
        }
#pragma unroll
        for (int j = 0; j < 8; ++j) {
            s0 += u2f(v[j] << 16) * dv[j];
            s1 += u2f(v[j] & 0xFFFF0000u) * dv[j];
        }
    }
    // overflow edges: ONLY nodes whose degree exceeded ELLW scan the list
    if (deg > ELLW) {
        int novf = *ovf_cnt;
        if (novf > OVF_CAP) novf = OVF_CAP;
        for (int k = 0; k < novf; ++k) {
            int2 q2 = ovf[k];
            if (q2.x == node) {
                float dw = rsqrtf(fmaxf((float)cnt[q2.y], 1.f));
                unsigned v = Xu[(size_t)q2.y * 64 + l];
                s0 += u2f(v << 16) * dw;
                s1 += u2f(v & 0xFFFF0000u) * dw;
            }
        }
    }

    float di = rsqrtf(fmaxf((float)deg, 1.f));
    ((unsigned*)out)[(size_t)node * 64 + l] = packbf(s0 * di, s1 * di);
}

// ---------------- conv1 GEMM (R11 structure) ----------------

static __global__ __launch_bounds__(512) void k_gemm_conv(
    const short* __restrict__ X0, const short* __restrict__ X1, const short* __restrict__ X2,
    const short* __restrict__ Wbf, const float* __restrict__ bias,
    const float* __restrict__ bng, const float* __restrict__ bnb,
    const float* __restrict__ bnm, const float* __restrict__ bnv,
    int M, short* __restrict__ out) {
    __shared__ short As[2][128 * 32];
    __shared__ short Bs[2][128 * 32];

    const int nwg = gridDim.x;
    const int q = nwg >> 3, r = nwg & 7;
    const int xcd = blockIdx.x & 7, slot = blockIdx.x >> 3;
    const int flat = (xcd < r ? xcd * (q + 1) : r * (q + 1) + (xcd - r) * q) + slot;
    const int m0 = flat * 128;

    const int t = threadIdx.x;
    const int wv = t >> 6;
    const int ln = t & 63;
    const int wr = wv >> 2;
    const int wc = wv & 3;
    const int lr = ln & 15;
    const int lk = ln >> 4;

    const short* segs[3] = {X0, X1, X2};

    f32x4 acc[4][2];
#pragma unroll
    for (int i = 0; i < 4; ++i)
#pragma unroll
        for (int j = 0; j < 2; ++j) acc[i][j] = (f32x4){0.f, 0.f, 0.f, 0.f};

    auto issue = [&](int buf, int kt) {
        const short* Xp = segs[kt >> 7];
        const int klocal = kt & 127;
#pragma unroll
        for (int j = 0; j < 2; ++j) {
            int g = wv * 2 + j;
            int c = g * 64 + ln;
            if (g < 8) {
                int row = c >> 2, sl = c & 3;
                int gm = m0 + row;
                if (gm > M - 1) gm = M - 1;
                const short* src = &Xp[(size_t)gm * 128 + klocal + ((sl ^ ((row >> 1) & 3)) * 8)];
                GL2LDS16(src, &As[buf][g * 512]);
            } else {
                int cb = c - 512;
                int row = cb >> 2, sl = cb & 3;
                const short* src = &Wbf[(size_t)row * 384 + kt + ((sl ^ ((row >> 1) & 3)) * 8)];
                GL2LDS16(src, &Bs[buf][(g - 8) * 512]);
            }
        }
    };
    auto compute = [&](int buf) {
        bf16x8 af[4], bfr[2];
#pragma unroll
        for (int fi = 0; fi < 4; ++fi) {
            int row = wr * 64 + fi * 16 + lr;
            af[fi] = *(const bf16x8*)&As[buf][row * 32 + ((lk ^ ((row >> 1) & 3)) * 8)];
        }
#pragma unroll
        for (int fj = 0; fj < 2; ++fj) {
            int row = wc * 32 + fj * 16 + lr;
            bfr[fj] = *(const bf16x8*)&Bs[buf][row * 32 + ((lk ^ ((row >> 1) & 3)) * 8)];
        }
#pragma unroll
        for (int fi = 0; fi < 4; ++fi)
#pragma unroll
            for (int fj = 0; fj < 2; ++fj)
                acc[fi][fj] = __builtin_amdgcn_mfma_f32_16x16x32_bf16(af[fi], bfr[fj], acc[fi][fj], 0, 0, 0);
    };

    issue(0, 0);
    __syncthreads();
#pragma unroll
    for (int tgt = 0; tgt < 12; ++tgt) {
        if (tgt < 11) issue((tgt + 1) & 1, (tgt + 1) * 32);
        compute(tgt & 1);
        __syncthreads();
    }

#pragma unroll
    for (int fi = 0; fi < 4; ++fi) {
#pragma unroll
        for (int reg = 0; reg < 4; ++reg) {
            int gm = m0 + wr * 64 + fi * 16 + lk * 4 + reg;
            if (gm >= M) continue;
#pragma unroll
            for (int fj = 0; fj < 2; ++fj) {
                int gn = wc * 32 + fj * 16 + lr;
                float y = fmaxf(acc[fi][fj][reg] + bias[gn], 0.f);
                float sc = rsqrtf(bnv[gn] + 1e-5f) * bng[gn];
                y = (y - bnm[gn]) * sc + bnb[gn];
                out[(size_t)gm * 128 + gn] = f2bf(y);
            }
        }
    }
}

// ---------------- conv2 GEMM + fused MLP ----------------

static __global__ __launch_bounds__(512) void k_gemm_mlp(
    const short* __restrict__ X0, const short* __restrict__ X1, const short* __restrict__ X2,
    const short* __restrict__ Wbf, const float* __restrict__ bias,
    const short* __restrict__ res,
    const short* __restrict__ Wm1bf, const float* __restrict__ bm1,
    const short* __restrict__ Wm2bf, const float* __restrict__ bm2,
    int M, float* __restrict__ out) {
    __shared__ __align__(16) short smem[25600];
    short* As0 = smem;
    short* As1 = smem + 4096;
    short* Bs0 = smem + 8192;
    short* Bs1 = smem + 12288;
    short* hs  = smem;            // [128][136] after GEMM phase
    short* Wst = smem + 17408;    // 2 x 4096 (MLP1) / 8192 whole-Wm2 (MLP2)

    const int nwg = gridDim.x;
    const int q = nwg >> 3, r = nwg & 7;
    const int xcd = blockIdx.x & 7, slot = blockIdx.x >> 3;
    const int flat = (xcd < r ? xcd * (q + 1) : r * (q + 1) + (xcd - r) * q) + slot;
    const int m0 = flat * 128;

    const int t = threadIdx.x;
    const int wv = t >> 6;
    const int ln = t & 63;
    const int wr = wv >> 2;
    const int wc = wv & 3;
    const int lr = ln & 15;
    const int lk = ln >> 4;

    const short* segs[3] = {X0, X1, X2};

    f32x4 acc[4][2];
#pragma unroll
    for (int i = 0; i < 4; ++i)
#pragma unroll
        for (int j = 0; j < 2; ++j) acc[i][j] = (f32x4){0.f, 0.f, 0.f, 0.f};

    auto issue = [&](int buf, int kt) {
        const short* Xp = segs[kt >> 7];
        const int klocal = kt & 127;
        short* Ab = buf ? As1 : As0;
        short* Bb = buf ? Bs1 : Bs0;
#pragma unroll
        for (int j = 0; j < 2; ++j) {
            int g = wv * 2 + j;
            int c = g * 64 + ln;
            if (g < 8) {
                int row = c >> 2, sl = c & 3;
                int gm = m0 + row;
                if (gm > M - 1) gm = M - 1;
                const short* src = &Xp[(size_t)gm * 128 + klocal + ((sl ^ ((row >> 1) & 3)) * 8)];
                GL2LDS16(src, &Ab[g * 512]);
            } else {
                int cb = c - 512;
                int row = cb >> 2, sl = cb & 3;
                const short* src = &Wbf[(size_t)row * 384 + kt + ((sl ^ ((row >> 1) & 3)) * 8)];
                GL2LDS16(src, &Bb[(g - 8) * 512]);
            }
        }
    };
    auto compute = [&](int buf) {
        short* Ab = buf ? As1 : As0;
        short* Bb = buf ? Bs1 : Bs0;
        bf16x8 af[4], bfr[2];
#pragma unroll
        for (int fi = 0; fi < 4; ++fi) {
            int row = wr * 64 + fi * 16 + lr;
            af[fi] = *(const bf16x8*)&Ab[row * 32 + ((lk ^ ((row >> 1) & 3)) * 8)];
        }
#pragma unroll
        for (int fj = 0; fj < 2; ++fj) {
            int row = wc * 32 + fj * 16 + lr;
            bfr[fj] = *(const bf16x8*)&Bb[row * 32 + ((lk ^ ((row >> 1) & 3)) * 8)];
        }
#pragma unroll
        for (int fi = 0; fi < 4; ++fi)
#pragma unroll
            for (int fj = 0; fj < 2; ++fj)
                acc[fi][fj] = __builtin_amdgcn_mfma_f32_16x16x32_bf16(af[fi], bfr[fj], acc[fi][fj], 0, 0, 0);
    };

    issue(0, 0);
    __syncthreads();
#pragma unroll
    for (int tgt = 0; tgt < 12; ++tgt) {
        if (tgt < 11) issue((tgt + 1) & 1, (tgt + 1) * 32);
        compute(tgt & 1);
        __syncthreads();
    }

    auto issueW1 = [&](int buf, int kt) {
        int c = t;
        int row = c >> 2, sl = c & 3;
        const short* src = &Wm1bf[(size_t)row * 128 + kt + ((sl ^ ((row >> 1) & 3)) * 8)];
        GL2LDS16(src, &Wst[buf * 4096 + c * 8]);
    };
    issueW1(0, 0);

#pragma unroll
    for (int fi = 0; fi < 4; ++fi) {
#pragma unroll
        for (int reg = 0; reg < 4; ++reg) {
            int row = wr * 64 + fi * 16 + lk * 4 + reg;
            int gm = m0 + row;
            int gr = gm < M ? gm : M - 1;
#pragma unroll
            for (int fj = 0; fj < 2; ++fj) {
                int gn = wc * 32 + fj * 16 + lr;
                float y = fmaxf(acc[fi][fj][reg] + bias[gn], 0.f) + bf2f(res[(size_t)gr * 128 + gn]);
                hs[row * 136 + gn] = f2bf(y);
            }
        }
    }
    __syncthreads();

    f32x4 acc2[4][2];
#pragma unroll
    for (int i = 0; i < 4; ++i)
#pragma unroll
        for (int j = 0; j < 2; ++j) acc2[i][j] = (f32x4){0.f, 0.f, 0.f, 0.f};

#pragma unroll
    for (int s = 0; s < 4; ++s) {
        if (s < 3) issueW1((s + 1) & 1, (s + 1) * 32);
        int kt = s * 32;
        short* Wb = &Wst[(s & 1) * 4096];
        bf16x8 af[4], bw[2];
#pragma unroll
        for (int fi = 0; fi < 4; ++fi) {
            int row = wr * 64 + fi * 16 + lr;
            af[fi] = *(const bf16x8*)&hs[row * 136 + kt + lk * 8];
        }
#pragma unroll
        for (int fj = 0; fj < 2; ++fj) {
            int row = wc * 32 + fj * 16 + lr;
            bw[fj] = *(const bf16x8*)&Wb[row * 32 + ((lk ^ ((row >> 1) & 3)) * 8)];
        }
#pragma unroll
        for (int fi = 0; fi < 4; ++fi)
#pragma unroll
            for (int fj = 0; fj < 2; ++fj)
                acc2[fi][fj] = __builtin_amdgcn_mfma_f32_16x16x32_bf16(af[fi], bw[fj], acc2[fi][fj], 0, 0, 0);
        __syncthreads();
    }

#pragma unroll
    for (int j = 0; j < 2; ++j) {
        int c = j * 512 + t;
        int row = c >> 4, s = c & 15;
        const short* src = &Wm2bf[(size_t)row * 128 + ((s ^ (row & 7)) * 8)];
        GL2LDS16(src, &Wst[c * 8]);
    }
#pragma unroll
    for (int fi = 0; fi < 4; ++fi) {
#pragma unroll
        for (int reg = 0; reg < 4; ++reg) {
            int row = wr * 64 + fi * 16 + lk * 4 + reg;
#pragma unroll
            for (int fj = 0; fj < 2; ++fj) {
                int col = wc * 32 + fj * 16 + lr;
                hs[row * 136 + col] = f2bf(fmaxf(acc2[fi][fj][reg] + bm1[col], 0.f));
            }
        }
    }
    __syncthreads();

    f32x4 acc3[4];
#pragma unroll
    for (int i = 0; i < 4; ++i) acc3[i] = (f32x4){0.f, 0.f, 0.f, 0.f};
#pragma unroll
    for (int s = 0; s < 4; ++s) {
        int kt = s * 32;
        bf16x8 af, bw;
        int brow = wc * 16 + lr;
        int sidx = s * 4 + lk;
        bw = *(const bf16x8*)&Wst[brow * 128 + ((sidx ^ (brow & 7)) * 8)];
#pragma unroll
        for (int fi = 0; fi < 4; ++fi) {
            int row = wr * 64 + fi * 16 + lr;
            af = *(const bf16x8*)&hs[row * 136 + kt + lk * 8];
            acc3[fi] = __builtin_amdgcn_mfma_f32_16x16x32_bf16(af, bw, acc3[fi], 0, 0, 0);
        }
    }

#pragma unroll
    for (int fi = 0; fi < 4; ++fi) {
#pragma unroll
        for (int reg = 0; reg < 4; ++reg) {
            int gm = m0 + wr * 64 + fi * 16 + lk * 4 + reg;
            if (gm >= M) continue;
            int col = wc * 16 + lr;
            out[(size_t)gm * 64 + col] = acc3[fi][reg] + bm2[col];
        }
    }
}

// ---------------- launch ----------------

extern "C" void kernel_launch(void* const* d_in, const int* in_sizes, int n_in,
                              void* d_out, int out_size, void* d_ws, size_t ws_size,
                              hipStream_t stream) {
    const float* features = (const float*)d_in[0];
    const int*   esrc     = (const int*)d_in[1];
    const int*   edst     = (const int*)d_in[2];
    const float* W1   = (const float*)d_in[3];
    const float* b1   = (const float*)d_in[4];
    const float* bng  = (const float*)d_in[5];
    const float* bnb  = (const float*)d_in[6];
    const float* bnm  = (const float*)d_in[7];
    const float* bnv  = (const float*)d_in[8];
    const float* W3   = (const float*)d_in[9];
    const float* b3   = (const float*)d_in[10];
    const float* Wm1  = (const float*)d_in[11];
    const float* bm1  = (const float*)d_in[12];
    const float* Wm2  = (const float*)d_in[13];
    const float* bm2  = (const float*)d_in[14];
    float* out = (float*)d_out;

    const int n  = in_sizes[0] / NF;     // 100000
    const int ne = in_sizes[1];          // 600000

    uint8_t* w = (uint8_t*)d_ws;
    size_t off = 0;
    auto alloc = [&](size_t bytes) -> void* {
        void* p = w + off;
        off = (off + bytes + 255) & ~(size_t)255;
        return p;
    };
    int* cnt      = (int*)alloc(((size_t)n + 1) * 4);   // [n] counts + [n] = ovf_cnt
    int* ell      = (int*)alloc((size_t)n * ELLW * 4);
    int2* ell2    = (int2*)alloc((size_t)n * ELLW * 8);
    int2* ovf     = (int2*)alloc((size_t)OVF_CAP * 8);
    short* fbf    = (short*)alloc((size_t)n * NF * 2);
    short* bufB   = (short*)alloc((size_t)n * NF * 2);   // Z1
    short* bufC   = (short*)alloc((size_t)n * NF * 2);   // Z2'
    short* bufD   = (short*)alloc((size_t)n * NF * 2);   // h1 (conv1 out, residual)
    short* W1bf   = (short*)alloc((size_t)128 * 384 * 2);  // folded
    short* W3bf   = (short*)alloc((size_t)128 * 384 * 2);  // folded
    short* Wm1bf  = (short*)alloc((size_t)128 * 128 * 2);
    short* Wm2bf  = (short*)alloc((size_t)64 * 128 * 2);
    (void)ws_size;
    int* ovf_cnt = cnt + n;

    const int TB = 256;
    const int nbE = (ne + TB - 1) / TB;
    const int n8  = n * NF / 8;
    const int nbF = (n8 + TB - 1) / TB;

    hipMemsetAsync(cnt, 0, ((size_t)n + 1) * 4, stream);
    k_pro<<<nbE + nbF + 60, TB, 0, stream>>>(esrc, edst, ne, cnt, ell, ovf_cnt, ovf,
                                             features, fbf, n8, nbE, nbF,
                                             W1, W3, Wm1, Wm2, W1bf, W3bf, Wm1bf, Wm2bf);

    const int gm128 = (n + 127) / 128;
    const int nbL   = (n + 3) / 4;   // lap: 4 nodes per 256-thread block

    // ---- conv1:  Z1 = P X0 (build pairs);  Z2' = P Z1;  h1 = bn(relu(GEMM)) ----
    k_lap<true><<<nbL, 256, 0, stream>>>(fbf, cnt, ell, ell2, ovf_cnt, ovf, bufB, n);
    k_lap<false><<<nbL, 256, 0, stream>>>(bufB, cnt, ell, ell2, ovf_cnt, ovf, bufC, n);
    k_gemm_conv<<<gm128, 512, 0, stream>>>(fbf, bufB, bufC, W1bf, b1,
                                           bng, bnb, bnm, bnv, n, bufD);

    // ---- conv2 + fused MLP ----
    k_lap<false><<<nbL, 256, 0, stream>>>(bufD, cnt, ell, ell2, ovf_cnt, ovf, bufB, n);
    k_lap<false><<<nbL, 256, 0, stream>>>(bufB, cnt, ell, ell2, ovf_cnt, ovf, bufC, n);
    k_gemm_mlp<<<gm128, 512, 0, stream>>>(bufD, bufB, bufC, W3bf, b3, bufD,
                                          Wm1bf, bm1, Wm2bf, bm2, n, out);
}